// Round 2
// 160.917 us; speedup vs baseline: 1.0543x; 1.0543x over previous
//
#include <hip/hip_runtime.h>
#include <stdint.h>
#include <string.h>

#define BB 8
#define NN 4096
#define DD 256
#define SCALE 0.0625f
#define XS 264   // xtile stride (shorts): [64 tok][256 d] bf16, 16B-aligned rows
#define XT 72    // Bs / Pl stride (shorts): 144B rows, 16B-aligned

using frag_ab = __attribute__((ext_vector_type(8))) short;   // 8 bf16
using frag_cd = __attribute__((ext_vector_type(4))) float;   // 4 fp32

__device__ __forceinline__ unsigned short f2bf(float f) {
    union { float f; unsigned u; } a; a.f = f;
    unsigned r = a.u + 0x7FFFu + ((a.u >> 16) & 1u);
    return (unsigned short)(r >> 16);
}
__device__ __forceinline__ float bf2f(unsigned short h) {
    union { unsigned u; float f; } a; a.u = ((unsigned)h) << 16;
    return a.f;
}

// ---- K1 setup (single launch, 385 blocks):
// bx<128: P12t row (on-the-fly agent proj) + c2 for stage2 cols
// bx in [128,384): W3b row i = bf16((W_v@W_fc1@W_fc2)[i])
// bx==384: b3
__global__ __launch_bounds__(256) void k_setup(
    const float* __restrict__ agent, const float* __restrict__ Wag,
    const float* __restrict__ bag, const float* __restrict__ Wqkv,
    const float* __restrict__ bqkv, const float* __restrict__ Wfc1,
    const float* __restrict__ bfc1, const float* __restrict__ Wfc2,
    unsigned short* __restrict__ P12t, float* __restrict__ c2,
    unsigned short* __restrict__ W3b, float* __restrict__ b3)
{
    __shared__ float arow[256];
    __shared__ float red[256];
    const int bx = blockIdx.x, tid = threadIdx.x;
    if (bx < 128) {
        const int c = bx;
        const int woff = (c < 64) ? 256 : 0;   // W_k for stage1, W_q for stage2
        const int aoff = (c < 64) ? 0 : 256;   // q_agent / k_agent
        const int row = c & 63;
        float s = bag[aoff + tid];
        for (int o = 0; o < 256; ++o) s += agent[row * 256 + o] * Wag[o * 512 + aoff + tid];
        arow[tid] = s;
        __syncthreads();
        float p = 0.f;
        for (int o = 0; o < 256; ++o) p += Wqkv[tid * 768 + woff + o] * arow[o];
        P12t[(size_t)c * 256 + tid] = f2bf(SCALE * p);
        if (c >= 64) {
            red[tid] = bqkv[woff + tid] * arow[tid];
            __syncthreads();
            for (int st = 128; st; st >>= 1) {
                if (tid < st) red[tid] += red[tid + st];
                __syncthreads();
            }
            if (tid == 0) c2[c - 64] = SCALE * red[0];
        }
    } else if (bx < 384) {
        const int i = bx - 128;
        float t = 0.f;
        for (int o = 0; o < 256; ++o) t += Wqkv[i * 768 + 512 + o] * Wfc1[o * 256 + tid];
        arow[tid] = t;
        __syncthreads();
        float p = 0.f;
        for (int k = 0; k < 256; ++k) p += arow[k] * Wfc2[k * 256 + tid];
        W3b[(size_t)i * 256 + tid] = f2bf(p);
    } else {
        float t = bfc1[tid];
        for (int o = 0; o < 256; ++o) t += bqkv[512 + o] * Wfc1[o * 256 + tid];
        arow[tid] = t;
        __syncthreads();
        float p = 0.f;
        for (int k = 0; k < 256; ++k) p += arow[k] * Wfc2[k * 256 + tid];
        b3[tid] = p;
    }
}

// ---- K2 fused, NO LDS aliasing: per 64-token chunk:
//  x -> bf16 xtile (write-once) -> logits[64x128] MFMA ->
//  {stage2 softmax -> p2b, stage1 exp -> Pl lds + chunk sums -> statS} ->
//  unnormalized Pl @ x^T MFMA (B-frags read as strided u16 columns of xtile)
//  -> part. Normalization deferred to k_fc.
__global__ __launch_bounds__(256) void k_fuse(
    const float* __restrict__ x, const unsigned short* __restrict__ P12t,
    const float* __restrict__ c2, unsigned short* __restrict__ p2b,
    unsigned short* __restrict__ part, float* __restrict__ statS)
{
    __shared__ unsigned short xtile[64 * XS];   // 33792 B, written Phase A only
    __shared__ unsigned short Bs[128 * XT];     // 18432 B, Phase B staging only
    __shared__ unsigned short Pl[64 * XT];      //  9216 B, written Phase D only
    __shared__ float Ss[4][64];                 //  1024 B  (total 62464 B)
    const int s = blockIdx.x, b = blockIdx.y;
    const int n0 = s * 64;
    const int tid = threadIdx.x;
    const int w = tid >> 6, lane = tid & 63;
    const int ml = lane & 15, q = lane >> 4;

    // Phase A: x fp32 -> xtile bf16 (fully coalesced)
#pragma unroll
    for (int p = 0; p < 16; ++p) {
        int idx = p * 256 + tid;
        int tok = idx >> 6, d = (idx & 63) * 4;
        float4 v = *(const float4*)&x[(size_t)(b * 4096 + n0 + tok) * 256 + d];
        unsigned short u[4] = {f2bf(v.x), f2bf(v.y), f2bf(v.z), f2bf(v.w)};
        uint2 pk; memcpy(&pk, u, 8);
        *(uint2*)&xtile[tok * XS + d] = pk;
    }
    __syncthreads();

    // Phase B: logits = xtile @ P12t^T, wave w owns toks w*16..w*16+15, 128 cols
    frag_cd acc1[8];
#pragma unroll
    for (int j = 0; j < 8; ++j)
#pragma unroll
        for (int r = 0; r < 4; ++r) acc1[j][r] = 0.f;

    for (int kb = 0; kb < 256; kb += 64) {
        __syncthreads();
#pragma unroll
        for (int p = 0; p < 4; ++p) {
            int idx = p * 256 + tid;
            int r = idx >> 3, c = (idx & 7) * 8;
            *(uint4*)&Bs[r * XT + c] = *(const uint4*)&P12t[(size_t)r * 256 + kb + c];
        }
        __syncthreads();
#pragma unroll
        for (int ks = 0; ks < 2; ++ks) {
            const int kk = ks * 32 + q * 8;
            frag_ab a = *(const frag_ab*)&xtile[(w * 16 + ml) * XS + kb + kk];
#pragma unroll
            for (int j = 0; j < 8; ++j) {
                frag_ab bf = *(const frag_ab*)&Bs[(j * 16 + ml) * XT + kk];
                acc1[j] = __builtin_amdgcn_mfma_f32_16x16x32_bf16(a, bf, acc1[j], 0, 0, 0);
            }
        }
    }

    // Phase C1: stage2 softmax over 64 agents (cols 64..127, bias c2) -> p2b
    {
        float cc[4];
#pragma unroll
        for (int j = 0; j < 4; ++j) cc[j] = c2[j * 16 + ml];
#pragma unroll
        for (int r = 0; r < 4; ++r) {
            float e[4], sum = 0.f;
#pragma unroll
            for (int j = 0; j < 4; ++j) {
                e[j] = __expf(acc1[4 + j][r] + cc[j]);
                sum += e[j];
            }
#pragma unroll
            for (int mask = 1; mask <= 8; mask <<= 1) sum += __shfl_xor(sum, mask);
            float inv = 1.f / sum;
            const int tok = n0 + w * 16 + q * 4 + r;
#pragma unroll
            for (int j = 0; j < 4; ++j)
                p2b[(size_t)(b * 4096 + tok) * 64 + j * 16 + ml] = f2bf(e[j] * inv);
        }
    }

    // Phase C2: stage1 exp (unnormalized, |logit|~O(6), no max needed) + sums
    float e1[4][4];
#pragma unroll
    for (int j = 0; j < 4; ++j) {
#pragma unroll
        for (int r = 0; r < 4; ++r) e1[j][r] = __expf(acc1[j][r]);
        float sj = e1[j][0] + e1[j][1] + e1[j][2] + e1[j][3];
        sj += __shfl_xor(sj, 16);
        sj += __shfl_xor(sj, 32);
        if (lane < 16) Ss[w][j * 16 + ml] = sj;
    }

    // Phase D: write Pl[agent][tok] (dedicated array, first-ever access)
#pragma unroll
    for (int j = 0; j < 4; ++j)
#pragma unroll
        for (int r = 0; r < 4; ++r)
            Pl[(j * 16 + ml) * XT + w * 16 + q * 4 + r] = f2bf(e1[j][r]);
    __syncthreads();   // covers Pl writes->reads and Ss writes->statS read

    if (tid < 64)
        statS[(size_t)(b * 64 + tid) * 64 + s] =
            Ss[0][tid] + Ss[1][tid] + Ss[2][tid] + Ss[3][tid];

    // Phase E: part[ag][d] = Pl[ag][tok] * x[tok][d], k = 64 toks.
    // B-fragment: column d of xtile, 8 strided u16 reads (stride 132 dwords
    // -> bank step 4, benign). xtile is immutable; no transpose needed.
    frag_cd acc2[4][4];
#pragma unroll
    for (int af = 0; af < 4; ++af)
#pragma unroll
        for (int i = 0; i < 4; ++i)
#pragma unroll
            for (int r = 0; r < 4; ++r) acc2[af][i][r] = 0.f;
#pragma unroll
    for (int ks = 0; ks < 2; ++ks) {
        const int kk = ks * 32 + q * 8;
        frag_ab a[4], bf[4];
#pragma unroll
        for (int af = 0; af < 4; ++af)
            a[af] = *(const frag_ab*)&Pl[(af * 16 + ml) * XT + kk];
#pragma unroll
        for (int i = 0; i < 4; ++i) {
            const int d = w * 64 + i * 16 + ml;
            unsigned short u[8];
#pragma unroll
            for (int t = 0; t < 8; ++t) u[t] = xtile[(kk + t) * XS + d];
            memcpy(&bf[i], u, 16);
        }
#pragma unroll
        for (int af = 0; af < 4; ++af)
#pragma unroll
            for (int i = 0; i < 4; ++i)
                acc2[af][i] = __builtin_amdgcn_mfma_f32_16x16x32_bf16(
                    a[af], bf[i], acc2[af][i], 0, 0, 0);
    }
#pragma unroll
    for (int af = 0; af < 4; ++af)
#pragma unroll
        for (int i = 0; i < 4; ++i)
#pragma unroll
            for (int r = 0; r < 4; ++r)
                part[(size_t)((s * 8 + b) * 64 + af * 16 + q * 4 + r) * 256 +
                     w * 64 + i * 16 + ml] = f2bf(acc2[af][i][r]);
}

// ---- K3: reduce 64 bf16 partials, apply deferred 1/rowsum, @W3b + b3 -> va3t
__global__ __launch_bounds__(256) void k_fc(
    const unsigned short* __restrict__ part, const float* __restrict__ statS,
    const unsigned short* __restrict__ W3b, const float* __restrict__ b3,
    unsigned short* __restrict__ va3t)
{
    __shared__ float rowb[256];
    __shared__ float rs[64];
    const int row = blockIdx.x, tid = threadIdx.x;
    const int b = row >> 6, agc = row & 63;
    if (tid < 64) rs[tid] = statS[(size_t)(b * 64 + agc) * 64 + tid];
    float sv = 0.f;
    for (int s = 0; s < 64; ++s)
        sv += bf2f(part[(size_t)((s * 8 + b) * 64 + agc) * 256 + tid]);
    __syncthreads();
    float tot = 0.f;
#pragma unroll
    for (int t = 0; t < 64; ++t) tot += rs[t];
    rowb[tid] = sv / tot;
    __syncthreads();
    float s2 = b3[tid];
    for (int k = 0; k < 256; ++k) s2 += rowb[k] * bf2f(W3b[(size_t)k * 256 + tid]);
    va3t[(size_t)(b * 256 + tid) * 64 + agc] = f2bf(s2);
}

// ---- K4: stage2: C[d][tok] = va3t @ P2^T (A=va3, B=P2) + b_fc2 + x ----
__global__ __launch_bounds__(256) void k_stage2(
    const unsigned short* __restrict__ p2b, const unsigned short* __restrict__ va3t,
    const float* __restrict__ x, const float* __restrict__ bfc2,
    float* __restrict__ out)
{
    __shared__ unsigned short Vs[256 * 72];  // d x agents
    __shared__ unsigned short Ps[64 * 72];   // tok x agents
    const int n0 = blockIdx.x * 64, b = blockIdx.y;
    const int tid = threadIdx.x;
    const int w = tid >> 6, lane = tid & 63;
    const int ml = lane & 15, q = lane >> 4;

#pragma unroll
    for (int p = 0; p < 8; ++p) {
        int idx = p * 256 + tid;
        int r = idx >> 3, c = (idx & 7) * 8;
        *(uint4*)&Vs[r * 72 + c] = *(const uint4*)&va3t[(size_t)(b * 256 + r) * 64 + c];
    }
#pragma unroll
    for (int p = 0; p < 2; ++p) {
        int idx = p * 256 + tid;
        int r = idx >> 3, c = (idx & 7) * 8;
        *(uint4*)&Ps[r * 72 + c] = *(const uint4*)&p2b[(size_t)(b * 4096 + n0 + r) * 64 + c];
    }
    __syncthreads();

    frag_cd acc[4][4];
#pragma unroll
    for (int i = 0; i < 4; ++i)
#pragma unroll
        for (int j = 0; j < 4; ++j)
#pragma unroll
            for (int r = 0; r < 4; ++r) acc[i][j][r] = 0.f;
#pragma unroll
    for (int ks = 0; ks < 2; ++ks) {
        const int kk = ks * 32 + q * 8;
        frag_ab a[4], bf[4];
#pragma unroll
        for (int i = 0; i < 4; ++i)
            a[i] = *(const frag_ab*)&Vs[(w * 64 + i * 16 + ml) * 72 + kk];
#pragma unroll
        for (int j = 0; j < 4; ++j)
            bf[j] = *(const frag_ab*)&Ps[(j * 16 + ml) * 72 + kk];
#pragma unroll
        for (int i = 0; i < 4; ++i)
#pragma unroll
            for (int j = 0; j < 4; ++j)
                acc[i][j] = __builtin_amdgcn_mfma_f32_16x16x32_bf16(
                    a[i], bf[j], acc[i][j], 0, 0, 0);
    }

#pragma unroll
    for (int i = 0; i < 4; ++i) {
        const int d0 = w * 64 + i * 16 + q * 4;
        float4 bias = *(const float4*)&bfc2[d0];
#pragma unroll
        for (int j = 0; j < 4; ++j) {
            const int tok = n0 + j * 16 + ml;
            size_t ad = (size_t)(b * 4096 + tok) * 256 + d0;
            float4 xr = *(const float4*)&x[ad];
            float4 o;
            o.x = acc[i][j][0] + bias.x + xr.x;
            o.y = acc[i][j][1] + bias.y + xr.y;
            o.z = acc[i][j][2] + bias.z + xr.z;
            o.w = acc[i][j][3] + bias.w + xr.w;
            *(float4*)&out[ad] = o;
        }
    }
}

extern "C" void kernel_launch(void* const* d_in, const int* in_sizes, int n_in,
                              void* d_out, int out_size, void* d_ws, size_t ws_size,
                              hipStream_t stream) {
    const float* agent = (const float*)d_in[0];
    const float* x     = (const float*)d_in[1];
    const float* Wqkv  = (const float*)d_in[2];
    const float* bqkv  = (const float*)d_in[3];
    const float* Wag   = (const float*)d_in[4];
    const float* bag   = (const float*)d_in[5];
    const float* Wfc1  = (const float*)d_in[6];
    const float* bfc1  = (const float*)d_in[7];
    const float* Wfc2  = (const float*)d_in[8];
    const float* bfc2  = (const float*)d_in[9];
    float* out = (float*)d_out;

    char* w = (char*)d_ws;
    size_t off = 0;
    unsigned short* p2b  = (unsigned short*)(w + off); off += (size_t)BB * NN * 64 * 2;       // 4.2 MB
    unsigned short* part = (unsigned short*)(w + off); off += (size_t)64 * BB * 64 * 256 * 2; // 16.8 MB
    float* statS = (float*)(w + off); off += (size_t)BB * 64 * 64 * 4;                        // 131 KB
    unsigned short* P12t = (unsigned short*)(w + off); off += (size_t)128 * 256 * 2;
    float* c2   = (float*)(w + off); off += 256 * 4;
    unsigned short* W3b = (unsigned short*)(w + off); off += (size_t)256 * 256 * 2;
    float* b3   = (float*)(w + off); off += 256 * 4;
    unsigned short* va3t = (unsigned short*)(w + off); off += (size_t)BB * DD * 64 * 2;

    k_setup<<<385, 256, 0, stream>>>(agent, Wag, bag, Wqkv, bqkv, Wfc1, bfc1, Wfc2,
                                     P12t, c2, W3b, b3);
    k_fuse<<<dim3(64, BB), 256, 0, stream>>>(x, P12t, c2, p2b, part, statS);
    k_fc<<<512, 256, 0, stream>>>(part, statS, W3b, b3, va3t);
    k_stage2<<<dim3(64, BB), 256, 0, stream>>>(p2b, va3t, x, bfc2, out);
}